// Round 8
// baseline (399.795 us; speedup 1.0000x reference)
//
#include <hip/hip_runtime.h>

// DiceLoss: loss1 = 2 * sum((inp > 0.5) * tgt); loss2 = sum(inp > 0.5) + sum(tgt)
// Round 6/7: block owns 1024 contiguous float4 per array (16 KB); thread t
// handles base+t+k*256, k=0..3. Coverage: 8192 blocks * 1024 = n4 exactly.
// One-shot burst: 8 independent float4 loads issued before any consumption.

__global__ __launch_bounds__(256) void dice_loss_kernel(
    const float* __restrict__ inp, const float* __restrict__ tgt,
    float* __restrict__ out, long long n4)
{
    const float4* __restrict__ in4 = (const float4*)inp;
    const float4* __restrict__ tg4 = (const float4*)tgt;

    const long long base = (long long)blockIdx.x * 1024 + threadIdx.x;

    float s_inter = 0.f, s_bin = 0.f, s_tgt = 0.f;

    if (base + 768 < n4) {
        // ---- issue all 8 loads before consuming anything ----
        float4 a0 = in4[base];
        float4 a1 = in4[base + 256];
        float4 a2 = in4[base + 512];
        float4 a3 = in4[base + 768];
        float4 b0 = tg4[base];
        float4 b1 = tg4[base + 256];
        float4 b2 = tg4[base + 512];
        float4 b3 = tg4[base + 768];

        #define ACC(a, b)                                              \
        {                                                              \
            float c0 = (a.x > 0.5f) ? 1.f : 0.f;                       \
            float c1 = (a.y > 0.5f) ? 1.f : 0.f;                       \
            float c2 = (a.z > 0.5f) ? 1.f : 0.f;                       \
            float c3 = (a.w > 0.5f) ? 1.f : 0.f;                       \
            s_bin   += (c0 + c1) + (c2 + c3);                          \
            s_tgt   += (b.x + b.y) + (b.z + b.w);                      \
            s_inter += (c0 * b.x + c1 * b.y) + (c2 * b.z + c3 * b.w);  \
        }
        ACC(a0, b0) ACC(a1, b1) ACC(a2, b2) ACC(a3, b3)
    } else {
        // generic tail (not taken at the benched shape)
        for (int k = 0; k < 4; ++k) {
            long long i = base + k * 256;
            if (i < n4) {
                float4 a = in4[i];
                float4 b = tg4[i];
                ACC(a, b)
            }
        }
    }
    #undef ACC

    // wave-64 shfl_down reduce
    #pragma unroll
    for (int off = 32; off > 0; off >>= 1) {
        s_inter += __shfl_down(s_inter, off, 64);
        s_bin   += __shfl_down(s_bin,   off, 64);
        s_tgt   += __shfl_down(s_tgt,   off, 64);
    }

    __shared__ float red[3][4];
    int wave = threadIdx.x >> 6;
    int lane = threadIdx.x & 63;
    if (lane == 0) {
        red[0][wave] = s_inter;
        red[1][wave] = s_bin;
        red[2][wave] = s_tgt;
    }
    __syncthreads();
    if (threadIdx.x == 0) {
        float ti = (red[0][0] + red[0][1]) + (red[0][2] + red[0][3]);
        float tb = (red[1][0] + red[1][1]) + (red[1][2] + red[1][3]);
        float tt = (red[2][0] + red[2][1]) + (red[2][2] + red[2][3]);
        atomicAdd(&out[0], 2.f * ti);     // loss1
        atomicAdd(&out[1], tb + tt);      // loss2
    }
}

extern "C" void kernel_launch(void* const* d_in, const int* in_sizes, int n_in,
                              void* d_out, int out_size, void* d_ws, size_t ws_size,
                              hipStream_t stream) {
    const float* inp = (const float*)d_in[0];
    const float* tgt = (const float*)d_in[1];
    float* out = (float*)d_out;

    long long n  = (long long)in_sizes[0];   // 33,554,432
    long long n4 = n / 4;                    // 8,388,608 float4 per input

    // d_out is re-poisoned to 0xAA before every timed launch — zero it.
    hipMemsetAsync(d_out, 0, 2 * sizeof(float), stream);

    const int block = 256;
    const int grid  = (int)((n4 + 1023) / 1024);  // 8192 for benched shape
    dice_loss_kernel<<<grid, block, 0, stream>>>(inp, tgt, out, n4);
}

// Round 9
// 280.435 us; speedup vs baseline: 1.4256x; 1.4256x over previous
//
#include <hip/hip_runtime.h>

// DiceLoss: loss1 = 2 * sum((inp > 0.5) * tgt); loss2 = sum(inp > 0.5) + sum(tgt)
// Round 9: REMOVE ATOMICS. Rounds 2/8 showed kernel time insensitive to
// HBM-vs-L3 residency and scaling with block count: same-cache-line
// atomicAdds serialized block retirement (4096 atomics=128us, 16384=222us).
// Stage 1: per-block partials plain-stored to d_ws (no atomics).
// Stage 2: one block reduces the partials and writes out[0..1].

#define T1 256

__global__ __launch_bounds__(T1) void dice_partial_kernel(
    const float* __restrict__ inp, const float* __restrict__ tgt,
    float* __restrict__ ws, long long n4, int P)
{
    const float4* __restrict__ in4 = (const float4*)inp;
    const float4* __restrict__ tg4 = (const float4*)tgt;

    // Block b owns float4 window [b*4096, (b+1)*4096) per array (64 KB).
    const long long wbase = (long long)blockIdx.x * 4096;
    const long long base  = wbase + threadIdx.x;

    float s_inter = 0.f, s_bin = 0.f, s_tgt = 0.f;

    #define ACC(a, b)                                              \
    {                                                              \
        float c0 = (a.x > 0.5f) ? 1.f : 0.f;                       \
        float c1 = (a.y > 0.5f) ? 1.f : 0.f;                       \
        float c2 = (a.z > 0.5f) ? 1.f : 0.f;                       \
        float c3 = (a.w > 0.5f) ? 1.f : 0.f;                       \
        s_bin   += (c0 + c1) + (c2 + c3);                          \
        s_tgt   += (b.x + b.y) + (b.z + b.w);                      \
        s_inter += (c0 * b.x + c1 * b.y) + (c2 * b.z + c3 * b.w);  \
    }

    if (wbase + 4096 <= n4) {
        // fast path: full window, 4 bursts of 8 independent float4 loads
        #pragma unroll
        for (int it = 0; it < 4; ++it) {
            long long i = base + (long long)it * 1024;
            float4 a0 = in4[i];
            float4 a1 = in4[i + 256];
            float4 a2 = in4[i + 512];
            float4 a3 = in4[i + 768];
            float4 b0 = tg4[i];
            float4 b1 = tg4[i + 256];
            float4 b2 = tg4[i + 512];
            float4 b3 = tg4[i + 768];
            ACC(a0, b0) ACC(a1, b1) ACC(a2, b2) ACC(a3, b3)
        }
    } else {
        // generic tail (not taken at the benched shape)
        for (int k = 0; k < 16; ++k) {
            long long i = base + (long long)k * 256;
            if (i < n4) {
                float4 a = in4[i];
                float4 b = tg4[i];
                ACC(a, b)
            }
        }
    }
    #undef ACC

    // wave-64 shfl_down reduce
    #pragma unroll
    for (int off = 32; off > 0; off >>= 1) {
        s_inter += __shfl_down(s_inter, off, 64);
        s_bin   += __shfl_down(s_bin,   off, 64);
        s_tgt   += __shfl_down(s_tgt,   off, 64);
    }

    __shared__ float red[3][4];
    int wave = threadIdx.x >> 6;
    int lane = threadIdx.x & 63;
    if (lane == 0) {
        red[0][wave] = s_inter;
        red[1][wave] = s_bin;
        red[2][wave] = s_tgt;
    }
    __syncthreads();
    if (threadIdx.x == 0) {
        // SoA partials: ws[0..P) = inter, ws[P..2P) = bin, ws[2P..3P) = tgt
        ws[            blockIdx.x] = (red[0][0] + red[0][1]) + (red[0][2] + red[0][3]);
        ws[    P + blockIdx.x] = (red[1][0] + red[1][1]) + (red[1][2] + red[1][3]);
        ws[2 * P + blockIdx.x] = (red[2][0] + red[2][1]) + (red[2][2] + red[2][3]);
    }
}

__global__ __launch_bounds__(T1) void dice_final_kernel(
    const float* __restrict__ ws, float* __restrict__ out, int P)
{
    float s0 = 0.f, s1 = 0.f, s2 = 0.f;
    for (int i = threadIdx.x; i < P; i += T1) {
        s0 += ws[i];
        s1 += ws[P + i];
        s2 += ws[2 * P + i];
    }
    #pragma unroll
    for (int off = 32; off > 0; off >>= 1) {
        s0 += __shfl_down(s0, off, 64);
        s1 += __shfl_down(s1, off, 64);
        s2 += __shfl_down(s2, off, 64);
    }
    __shared__ float red[3][4];
    int wave = threadIdx.x >> 6;
    int lane = threadIdx.x & 63;
    if (lane == 0) {
        red[0][wave] = s0;
        red[1][wave] = s1;
        red[2][wave] = s2;
    }
    __syncthreads();
    if (threadIdx.x == 0) {
        float ti = (red[0][0] + red[0][1]) + (red[0][2] + red[0][3]);
        float tb = (red[1][0] + red[1][1]) + (red[1][2] + red[1][3]);
        float tt = (red[2][0] + red[2][1]) + (red[2][2] + red[2][3]);
        out[0] = 2.f * ti;      // loss1
        out[1] = tb + tt;       // loss2
    }
}

extern "C" void kernel_launch(void* const* d_in, const int* in_sizes, int n_in,
                              void* d_out, int out_size, void* d_ws, size_t ws_size,
                              hipStream_t stream) {
    const float* inp = (const float*)d_in[0];
    const float* tgt = (const float*)d_in[1];
    float* out = (float*)d_out;
    float* ws  = (float*)d_ws;

    long long n  = (long long)in_sizes[0];   // 33,554,432
    long long n4 = n / 4;                    // 8,388,608 float4 per input

    const int grid1 = (int)((n4 + 4095) / 4096);   // 2048 at benched shape
    dice_partial_kernel<<<grid1, T1, 0, stream>>>(inp, tgt, ws, n4, grid1);
    dice_final_kernel<<<1, T1, 0, stream>>>(ws, out, grid1);
}

// Round 14
// 275.892 us; speedup vs baseline: 1.4491x; 1.0165x over previous
//
#include <hip/hip_runtime.h>

// DiceLoss: loss1 = 2 * sum((inp > 0.5) * tgt); loss2 = sum(inp > 0.5) + sum(tgt)
// Round 10-14: block-count experiment. Fit over rounds 2/3/8/9 gives
// T = 19ns * blocks + 65us -> per-WG dispatch cost dominates at 2048+ blocks.
// Now: 512 blocks (2/CU), each owns 256 KB/array contiguous window,
// launch_bounds(256,2) for deep VGPR load window, 8 fully-unrolled iters
// of 8+8 independent float4 loads. Two-stage reduce, zero atomics.

#define T1 256
#define WIN 16384LL   // float4 per array per block

__global__ __launch_bounds__(T1, 2) void dice_partial_kernel(
    const float* __restrict__ inp, const float* __restrict__ tgt,
    float* __restrict__ ws, long long n4, int P)
{
    const float4* __restrict__ in4 = (const float4*)inp;
    const float4* __restrict__ tg4 = (const float4*)tgt;

    const long long wbase = (long long)blockIdx.x * WIN;

    float s_inter = 0.f, s_bin = 0.f, s_tgt = 0.f;

    #define ACC(a, b)                                              \
    {                                                              \
        float c0 = (a.x > 0.5f) ? 1.f : 0.f;                       \
        float c1 = (a.y > 0.5f) ? 1.f : 0.f;                       \
        float c2 = (a.z > 0.5f) ? 1.f : 0.f;                       \
        float c3 = (a.w > 0.5f) ? 1.f : 0.f;                       \
        s_bin   += (c0 + c1) + (c2 + c3);                          \
        s_tgt   += (b.x + b.y) + (b.z + b.w);                      \
        s_inter += (c0 * b.x + c1 * b.y) + (c2 * b.z + c3 * b.w);  \
    }

    if (wbase + WIN <= n4) {
        const long long tb = wbase + threadIdx.x;
        #pragma unroll
        for (int k = 0; k < 8; ++k) {
            const long long i = tb + (long long)k * 2048;
            // 8+8 independent loads, named (no runtime-indexed arrays)
            float4 a0 = in4[i];
            float4 a1 = in4[i +  256];
            float4 a2 = in4[i +  512];
            float4 a3 = in4[i +  768];
            float4 a4 = in4[i + 1024];
            float4 a5 = in4[i + 1280];
            float4 a6 = in4[i + 1536];
            float4 a7 = in4[i + 1792];
            float4 b0 = tg4[i];
            float4 b1 = tg4[i +  256];
            float4 b2 = tg4[i +  512];
            float4 b3 = tg4[i +  768];
            float4 b4 = tg4[i + 1024];
            float4 b5 = tg4[i + 1280];
            float4 b6 = tg4[i + 1536];
            float4 b7 = tg4[i + 1792];
            ACC(a0, b0) ACC(a1, b1) ACC(a2, b2) ACC(a3, b3)
            ACC(a4, b4) ACC(a5, b5) ACC(a6, b6) ACC(a7, b7)
        }
    } else {
        // generic tail (not taken at the benched shape)
        for (long long i = wbase + threadIdx.x; i < n4 && i < wbase + WIN; i += T1) {
            float4 a = in4[i];
            float4 b = tg4[i];
            ACC(a, b)
        }
    }
    #undef ACC

    // wave-64 shfl_down reduce
    #pragma unroll
    for (int off = 32; off > 0; off >>= 1) {
        s_inter += __shfl_down(s_inter, off, 64);
        s_bin   += __shfl_down(s_bin,   off, 64);
        s_tgt   += __shfl_down(s_tgt,   off, 64);
    }

    __shared__ float red[3][4];
    int wave = threadIdx.x >> 6;
    int lane = threadIdx.x & 63;
    if (lane == 0) {
        red[0][wave] = s_inter;
        red[1][wave] = s_bin;
        red[2][wave] = s_tgt;
    }
    __syncthreads();
    if (threadIdx.x == 0) {
        // SoA partials: ws[0..P) = inter, ws[P..2P) = bin, ws[2P..3P) = tgt
        ws[        blockIdx.x] = (red[0][0] + red[0][1]) + (red[0][2] + red[0][3]);
        ws[    P + blockIdx.x] = (red[1][0] + red[1][1]) + (red[1][2] + red[1][3]);
        ws[2 * P + blockIdx.x] = (red[2][0] + red[2][1]) + (red[2][2] + red[2][3]);
    }
}

__global__ __launch_bounds__(T1) void dice_final_kernel(
    const float* __restrict__ ws, float* __restrict__ out, int P)
{
    float s0 = 0.f, s1 = 0.f, s2 = 0.f;
    for (int i = threadIdx.x; i < P; i += T1) {
        s0 += ws[i];
        s1 += ws[P + i];
        s2 += ws[2 * P + i];
    }
    #pragma unroll
    for (int off = 32; off > 0; off >>= 1) {
        s0 += __shfl_down(s0, off, 64);
        s1 += __shfl_down(s1, off, 64);
        s2 += __shfl_down(s2, off, 64);
    }
    __shared__ float red[3][4];
    int wave = threadIdx.x >> 6;
    int lane = threadIdx.x & 63;
    if (lane == 0) {
        red[0][wave] = s0;
        red[1][wave] = s1;
        red[2][wave] = s2;
    }
    __syncthreads();
    if (threadIdx.x == 0) {
        float ti = (red[0][0] + red[0][1]) + (red[0][2] + red[0][3]);
        float tb = (red[1][0] + red[1][1]) + (red[1][2] + red[1][3]);
        float tt = (red[2][0] + red[2][1]) + (red[2][2] + red[2][3]);
        out[0] = 2.f * ti;      // loss1
        out[1] = tb + tt;       // loss2
    }
}

extern "C" void kernel_launch(void* const* d_in, const int* in_sizes, int n_in,
                              void* d_out, int out_size, void* d_ws, size_t ws_size,
                              hipStream_t stream) {
    const float* inp = (const float*)d_in[0];
    const float* tgt = (const float*)d_in[1];
    float* out = (float*)d_out;
    float* ws  = (float*)d_ws;

    long long n  = (long long)in_sizes[0];   // 33,554,432
    long long n4 = n / 4;                    // 8,388,608 float4 per input

    const int grid1 = (int)((n4 + WIN - 1) / WIN);   // 512 at benched shape
    dice_partial_kernel<<<grid1, T1, 0, stream>>>(inp, tgt, ws, n4, grid1);
    dice_final_kernel<<<1, T1, 0, stream>>>(ws, out, grid1);
}